// Round 3
// baseline (480.500 us; speedup 1.0000x reference)
//
#include <hip/hip_runtime.h>
#include <hip/hip_bf16.h>

// Problem constants
#define BATCH   1024
#define FDIM    2048
#define LDIM    80
#define EDIM    512
#define ODIM    2048
#define NEXP    8
#define INDIM   2560   // FDIM + EDIM

typedef __bf16 bf16x8 __attribute__((ext_vector_type(8)));
typedef float  f32x4  __attribute__((ext_vector_type(4)));

__device__ __forceinline__ unsigned int pack2(float lo, float hi) {
    // fp32x2 -> packed bf16x2 (RNE); lowers to v_cvt_pk_bf16_f32
    __hip_bfloat162 h = __float22bfloat162_rn(make_float2(lo, hi));
    unsigned int u;
    __builtin_memcpy(&u, &h, 4);
    return u;
}
__device__ __forceinline__ float bf2f(unsigned short h) {
    return __uint_as_float((unsigned int)h << 16);
}
__device__ __forceinline__ void gload_lds16(const void* g, void* l) {
    // async global->LDS, 16B per lane; LDS dest = wave-uniform base + lane*16
    __builtin_amdgcn_global_load_lds(
        (__attribute__((address_space(1))) void*)g,
        (__attribute__((address_space(3))) void*)l,
        16, 0, 0);
}

// ---------------------------------------------------------------------------
// Kernel 0: W fp32 [e][k][o] -> Wb bf16 [e][o][k].
// Thread owns 4 consecutive o; float4 reads (coalesced 1KB/wave-instr);
// streams 8 k-rows per chunk; per-thread writes cover a full 64B span of each
// o-row (L2 merges the 4x16B stores into full lines).
// grid (ODIM/1024=2, INDIM/32=80, NEXP).
// ---------------------------------------------------------------------------
__global__ __launch_bounds__(256) void convert_w(
    const float* __restrict__ W, unsigned short* __restrict__ Wb)
{
    const int t     = threadIdx.x;
    const int obase = blockIdx.x * 1024 + t * 4;
    const int k0    = blockIdx.y * 32;
    const int e     = blockIdx.z;
    const float* src = W + (size_t)e * ((size_t)INDIM * ODIM) + (size_t)k0 * ODIM + obase;
    unsigned short* dst = Wb + (size_t)e * ((size_t)ODIM * INDIM) + (size_t)obase * INDIM + k0;

    #pragma unroll
    for (int c = 0; c < 4; ++c) {         // k-chunk: 8 k-rows -> 4 kpairs
        float4 r[8];
        #pragma unroll
        for (int j = 0; j < 8; ++j)
            r[j] = *(const float4*)(src + (size_t)(c * 8 + j) * ODIM);
        const float* rp = (const float*)r;  // rp[j*4 + i]
        #pragma unroll
        for (int i = 0; i < 4; ++i) {      // o offset within the 4 owned
            uint4 u;
            u.x = pack2(rp[0 * 4 + i], rp[1 * 4 + i]);
            u.y = pack2(rp[2 * 4 + i], rp[3 * 4 + i]);
            u.z = pack2(rp[4 * 4 + i], rp[5 * 4 + i]);
            u.w = pack2(rp[6 * 4 + i], rp[7 * 4 + i]);
            *(uint4*)(dst + (size_t)i * INDIM + c * 8) = u;
        }
    }
}

// ---------------------------------------------------------------------------
// Kernel 1: combined = [features | labels @ label_embed] as bf16, row-major
// ---------------------------------------------------------------------------
__global__ __launch_bounds__(256) void prep_kernel(
    const float* __restrict__ features, const float* __restrict__ labels,
    const float* __restrict__ label_embed, unsigned short* __restrict__ cb)
{
    const int b0 = blockIdx.x * 4;
    const int t  = threadIdx.x;
    __shared__ float lab[4][LDIM];
    for (int idx = t; idx < 4 * LDIM; idx += 256) {
        lab[idx / LDIM][idx % LDIM] = labels[(size_t)(b0 + idx / LDIM) * LDIM + (idx % LDIM)];
    }
    __syncthreads();

    {
        const int r = t >> 6, c64 = t & 63;
        const float4* F4 = (const float4*)features;
        #pragma unroll
        for (int ch = 0; ch < 8; ++ch) {
            float4 v = F4[(size_t)(b0 + r) * (FDIM / 4) + c64 + 64 * ch];
            uint2 pk;
            pk.x = pack2(v.x, v.y);
            pk.y = pack2(v.z, v.w);
            *(uint2*)(cb + (size_t)(b0 + r) * INDIM + (size_t)(c64 + 64 * ch) * 4) = pk;
        }
    }
    {
        const int j = 2 * t;
        float acc[4][2] = {{0,0},{0,0},{0,0},{0,0}};
        const float2* le2 = (const float2*)label_embed;
        for (int l = 0; l < LDIM; ++l) {
            float2 le = le2[(size_t)l * (EDIM / 2) + t];
            #pragma unroll
            for (int r = 0; r < 4; ++r) {
                float lv = lab[r][l];
                acc[r][0] += lv * le.x;
                acc[r][1] += lv * le.y;
            }
        }
        #pragma unroll
        for (int r = 0; r < 4; ++r) {
            *(unsigned int*)(cb + (size_t)(b0 + r) * INDIM + FDIM + j) = pack2(acc[r][0], acc[r][1]);
        }
    }
}

// ---------------------------------------------------------------------------
// Kernel 2: gating = sigmoid(combined @ gate_w + gate_b), AND pre-fill
// out[b][o] = sum_e g[b,e] * expert_b[e,o]  (replaces memset; gemm atomics
// accumulate g*acc on top). 1 block per batch row.
// ---------------------------------------------------------------------------
__global__ __launch_bounds__(256) void gate_kernel(
    const unsigned short* __restrict__ cb, const float* __restrict__ gw,
    const float* __restrict__ gb, const float* __restrict__ eb,
    float* __restrict__ gating, float* __restrict__ out)
{
    const int b = blockIdx.x, t = threadIdx.x;
    float p[NEXP] = {0,0,0,0,0,0,0,0};
    for (int i = t; i < INDIM; i += 256) {
        float c = bf2f(cb[(size_t)b * INDIM + i]);
        const float4* g4 = (const float4*)(gw + (size_t)i * NEXP);
        float4 u = g4[0], v = g4[1];
        p[0] += c * u.x; p[1] += c * u.y; p[2] += c * u.z; p[3] += c * u.w;
        p[4] += c * v.x; p[5] += c * v.y; p[6] += c * v.z; p[7] += c * v.w;
    }
    __shared__ float red[4][NEXP];
    __shared__ float g_sh[NEXP];
    const int lane = t & 63, wave = t >> 6;
    #pragma unroll
    for (int e = 0; e < NEXP; ++e) {
        float v = p[e];
        v += __shfl_down(v, 32); v += __shfl_down(v, 16); v += __shfl_down(v, 8);
        v += __shfl_down(v, 4);  v += __shfl_down(v, 2);  v += __shfl_down(v, 1);
        if (lane == 0) red[wave][e] = v;
    }
    __syncthreads();
    if (t < NEXP) {
        float s = red[0][t] + red[1][t] + red[2][t] + red[3][t] + gb[t];
        float g = 1.0f / (1.0f + __expf(-s));
        gating[(size_t)b * NEXP + t] = g;
        g_sh[t] = g;
    }
    __syncthreads();
    float g0 = g_sh[0], g1 = g_sh[1], g2 = g_sh[2], g3 = g_sh[3];
    float g4 = g_sh[4], g5 = g_sh[5], g6 = g_sh[6], g7 = g_sh[7];
    #pragma unroll
    for (int j = 0; j < 8; ++j) {
        const int o = t + 256 * j;
        float s = g0 * eb[0 * ODIM + o] + g1 * eb[1 * ODIM + o]
                + g2 * eb[2 * ODIM + o] + g3 * eb[3 * ODIM + o]
                + g4 * eb[4 * ODIM + o] + g5 * eb[5 * ODIM + o]
                + g6 * eb[6 * ODIM + o] + g7 * eb[7 * ODIM + o];
        out[(size_t)b * ODIM + o] = s;
    }
}

// ---------------------------------------------------------------------------
// Kernel 3: MoE GEMM. 128x128 tile, BK=64 via DUAL 32-wide LDS buffers
// (keeps 64B row stride => bank-minimal ds_read_b128). 40 K-iterations,
// 8 gload_lds16 + 16 ds_read_b128 + 32 MFMA per iteration, one barrier pair.
// Epilogue: atomic g*acc onto pre-biased out.
// ---------------------------------------------------------------------------
__global__ __launch_bounds__(256) void moe_gemm(
    const unsigned short* __restrict__ cb, const unsigned short* __restrict__ Wb,
    const float* __restrict__ gating, float* __restrict__ out)
{
    __shared__ unsigned short As[2][128 * 32];  // [khalf][m][k32], 64B rows
    __shared__ unsigned short Bs[2][128 * 32];  // [khalf][n][k32], 64B rows

    const int t = threadIdx.x;
    const int lane = t & 63, wave = t >> 6;
    const int n0 = blockIdx.x * 128;
    const int m0 = blockIdx.y * 128;
    const int e  = blockIdx.z;

    f32x4 acc[4][4];
    #pragma unroll
    for (int i = 0; i < 4; ++i)
        #pragma unroll
        for (int j = 0; j < 4; ++j) acc[i][j] = (f32x4){0.f, 0.f, 0.f, 0.f};

    // staging: row = t>>2, 16B chunk = t&3 (matches gload_lds lane order)
    const int srow = t >> 2, scg = t & 3;
    const unsigned short* ag0 = cb + (size_t)(m0 + srow) * INDIM + scg * 8;
    const unsigned short* bg0 = Wb + (size_t)e * ((size_t)ODIM * INDIM)
                                   + (size_t)(n0 + srow) * INDIM + scg * 8;
    unsigned short* alds[2][2];
    unsigned short* blds[2][2];
    #pragma unroll
    for (int h = 0; h < 2; ++h) {
        alds[h][0] = &As[h][0] + wave * 512;
        alds[h][1] = &As[h][0] + 2048 + wave * 512;
        blds[h][0] = &Bs[h][0] + wave * 512;
        blds[h][1] = &Bs[h][0] + 2048 + wave * 512;
    }

    const int fm = lane & 15, fq = lane >> 4;
    const int wn = (wave & 1) * 64;
    const int wm = (wave >> 1) * 64;

    for (int k0 = 0; k0 < INDIM; k0 += 64) {
        __syncthreads();
        #pragma unroll
        for (int h = 0; h < 2; ++h) {
            gload_lds16(ag0 + k0 + 32 * h, alds[h][0]);
            gload_lds16(ag0 + (size_t)64 * INDIM + k0 + 32 * h, alds[h][1]);
            gload_lds16(bg0 + k0 + 32 * h, blds[h][0]);
            gload_lds16(bg0 + (size_t)64 * INDIM + k0 + 32 * h, blds[h][1]);
        }
        __syncthreads();

        #pragma unroll
        for (int h = 0; h < 2; ++h) {
            bf16x8 af[4], bfr[4];
            #pragma unroll
            for (int mi = 0; mi < 4; ++mi)
                af[mi] = *(const bf16x8*)(&As[h][0] + (wm + mi * 16 + fm) * 32 + fq * 8);
            #pragma unroll
            for (int ni = 0; ni < 4; ++ni)
                bfr[ni] = *(const bf16x8*)(&Bs[h][0] + (wn + ni * 16 + fm) * 32 + fq * 8);
            #pragma unroll
            for (int mi = 0; mi < 4; ++mi)
                #pragma unroll
                for (int ni = 0; ni < 4; ++ni)
                    acc[mi][ni] = __builtin_amdgcn_mfma_f32_16x16x32_bf16(af[mi], bfr[ni], acc[mi][ni], 0, 0, 0);
        }
    }

    #pragma unroll
    for (int mi = 0; mi < 4; ++mi) {
        const int grow = m0 + wm + mi * 16 + fq * 4;  // C/D row = quad*4 + reg
        const float g0 = gating[(size_t)(grow + 0) * NEXP + e];
        const float g1 = gating[(size_t)(grow + 1) * NEXP + e];
        const float g2 = gating[(size_t)(grow + 2) * NEXP + e];
        const float g3 = gating[(size_t)(grow + 3) * NEXP + e];
        #pragma unroll
        for (int ni = 0; ni < 4; ++ni) {
            const int gcol = n0 + wn + ni * 16 + fm;  // C/D col = lane&15
            f32x4 a = acc[mi][ni];
            unsafeAtomicAdd(out + (size_t)(grow + 0) * ODIM + gcol, g0 * a.x);
            unsafeAtomicAdd(out + (size_t)(grow + 1) * ODIM + gcol, g1 * a.y);
            unsafeAtomicAdd(out + (size_t)(grow + 2) * ODIM + gcol, g2 * a.z);
            unsafeAtomicAdd(out + (size_t)(grow + 3) * ODIM + gcol, g3 * a.w);
        }
    }
}

// ---------------------------------------------------------------------------
extern "C" void kernel_launch(void* const* d_in, const int* in_sizes, int n_in,
                              void* d_out, int out_size, void* d_ws, size_t ws_size,
                              hipStream_t stream) {
    const float* features    = (const float*)d_in[0];
    const float* labels      = (const float*)d_in[1];
    const float* label_embed = (const float*)d_in[2];
    const float* gate_w      = (const float*)d_in[3];
    const float* gate_b      = (const float*)d_in[4];
    const float* expert_w    = (const float*)d_in[5];
    const float* expert_b    = (const float*)d_in[6];
    float* out = (float*)d_out;

    // ws layout: Wb bf16 [8][2048][2560] | cb bf16 [1024][2560] | gating f32
    const size_t wb_bytes = (size_t)NEXP * ODIM * INDIM * 2;   // 83,886,080
    const size_t cb_bytes = (size_t)BATCH * INDIM * 2;         //  5,242,880
    unsigned short* Wb = (unsigned short*)d_ws;
    unsigned short* cb = (unsigned short*)((char*)d_ws + wb_bytes);
    float* gating = (float*)((char*)d_ws + wb_bytes + cb_bytes);

    convert_w<<<dim3(ODIM / 1024, INDIM / 32, NEXP), 256, 0, stream>>>(expert_w, Wb);
    prep_kernel<<<BATCH / 4, 256, 0, stream>>>(features, labels, label_embed, cb);
    gate_kernel<<<BATCH, 256, 0, stream>>>(cb, gate_w, gate_b, expert_b, gating, out);
    moe_gemm<<<dim3(ODIM / 128, BATCH / 128, NEXP), 256, 0, stream>>>(cb, Wb, gating, out);
}